// Round 10
// baseline (189.291 us; speedup 1.0000x reference)
//
#include <hip/hip_runtime.h>
#include <stdint.h>

#define GAMMA 0.002f
#define MDIM 4096
#define NDIM 8192
#define KDIM 512

typedef short v8s __attribute__((ext_vector_type(8)));
typedef float v4f __attribute__((ext_vector_type(4)));

__device__ __forceinline__ unsigned short f32_to_bf16_rne(float f) {
    union { float f; uint32_t u; } v; v.f = f;
    uint32_t u = v.u;
    return (unsigned short)((u + 0x7fffu + ((u >> 16) & 1u)) >> 16);
}

__device__ __forceinline__ void gl_lds16(const void* g, void* l) {
    __builtin_amdgcn_global_load_lds(
        (const __attribute__((address_space(1))) uint32_t*)g,
        (__attribute__((address_space(3))) uint32_t*)l, 16, 0, 0);
}

// One block per row: convert 512 fp32 -> bf16 (RNE) and emit -gamma*sum(x^2).
__global__ __launch_bounds__(256) void convert_rows(
    const float* __restrict__ in, unsigned short* __restrict__ outb,
    float* __restrict__ neg_g_sq) {
    int row = blockIdx.x;
    const float* src = in + (size_t)row * KDIM;
    unsigned short* dst = outb + (size_t)row * KDIM;
    int t = threadIdx.x;
    float2 f = ((const float2*)src)[t];
    ushort2 b;
    b.x = f32_to_bf16_rne(f.x);
    b.y = f32_to_bf16_rne(f.y);
    ((ushort2*)dst)[t] = b;
    float s = f.x * f.x + f.y * f.y;
    #pragma unroll
    for (int off = 32; off > 0; off >>= 1) s += __shfl_down(s, off, 64);
    __shared__ float red[4];
    if ((t & 63) == 0) red[t >> 6] = s;
    __syncthreads();
    if (t == 0) neg_g_sq[row] = -GAMMA * (red[0] + red[1] + red[2] + red[3]);
}

// v8: TLP experiment. Block 256x128, 8 waves (4m x 2n), each wave the SAME
// 64x64 / acc4x4 / 8-fragment unit as v4-v7 (VGPR ~68). LDS = 3 x 24 KiB
// buffers + biases = 73.5 KiB -> 2 blocks/CU = 16 waves/CU (vs 12 before).
// v7 conflict-free paired-row geometry; counted vmcnt(3); L2 region
// 8mt x 16nt (2 MiB A + 2 MiB B per XCD); direct-store epilogue.
// C[m,n] = exp(arow[m] + ccol[n] + 2*gamma*dot(x[m], sv[n]))
__global__ __launch_bounds__(512, 4) void rbf_gemm(
    const unsigned short* __restrict__ A,   // [4096,512] bf16
    const unsigned short* __restrict__ B,   // [8192,512] bf16
    const float* __restrict__ arow,         // [4096]  = -g*||x||^2
    const float* __restrict__ ccol,         // [8192]  = -g*||sv||^2
    float* __restrict__ out) {

    // LDS: buffer b at b*24576: A [0..16383] (128 super-rows x 128 B,
    // super-row r = logical rows r and r+128), B [16384..24575] (64 super-rows,
    // pairs r/r+64). sb_r 256 f32 @73728, sb_c 128 f32 @74752. total 75264 B.
    __shared__ __align__(16) char smem[75264];

    const int tid  = threadIdx.x;
    const int lane = tid & 63;
    const int wave = tid >> 6;          // 0..7
    const int wm   = wave >> 1;         // 0..3 : 64-row slice of 256
    const int wn   = wave & 1;          // 0..1 : 64-col slice of 128

    // L2-aware partition: 1024 blocks; xcd = bid&7; region = 8 mt x 16 nt.
    const int bid = blockIdx.x;
    const int xcd = bid & 7;
    const int idx = bid >> 3;                        // 0..127
    const int mt  = ((xcd & 1) << 3) | (idx & 7);    // 0..15
    const int nt  = ((xcd >> 1) << 4) | (idx >> 3);  // 0..63
    const int row0 = mt << 8;
    const int col0 = nt << 7;

    // ---- staging (inverse-swizzled source, linear LDS dest) ----
    // A granules g = tid and tid+512: super-row rA = g>>3, stored col sG=g&7,
    // logical col lG = sG ^ (rA&7) -> half hi = lG>>2 (row + hi*128),
    // chunk c = lG&3. g+512 -> rA+64 (same sG, same lG) -> source +64 rows.
    const int rGa = tid >> 3;                        // 0..63
    const int sG  = tid & 7;
    const int lGa = sG ^ (rGa & 7);
    const char* aS = (const char*)A +
        ((size_t)(row0 + rGa + (lGa >> 2) * 128) << 10) + ((lGa & 3) << 4);
    // B granules g = tid: super-row rB = tid>>3 (0..63), pairs r/r+64.
    const char* bS = (const char*)B +
        ((size_t)(col0 + rGa + (lGa >> 2) * 64) << 10) + ((lGa & 3) << 4);
    char* dA = smem + tid * 16;                      // +8192 for g+512
    char* dB = smem + 16384 + tid * 16;

    #define STAGE(t)                                                          \
      do {                                                                    \
        const int _b = ((t) % 3) * 24576;                                     \
        const char* _sa = aS + (t) * 64;                                      \
        gl_lds16(_sa,          dA + _b);                                      \
        gl_lds16(_sa + 65536,  dA + _b + 8192);                               \
        gl_lds16(bS + (t) * 64, dB + _b);                                     \
      } while (0)

    // ---- fragment addresses (paired-row, conflict-free) ----
    const int q   = lane >> 4;          // 0..3 : k-chunk
    const int l15 = lane & 15;
    // A row = wm*64 + i*16 + l15 -> hi = wm>>1, super-row (wm&1)*64 + i*16 + l15
    const int aOff = ((wm & 1) * 64 + l15) * 128 +
                     (((((wm >> 1) << 2) | q) ^ (l15 & 7)) << 4);   // + i*2048
    const int bOff = 16384 + l15 * 128 +
                     ((((wn << 2) | q) ^ (l15 & 7)) << 4);          // + j*2048

    v4f acc[4][4];
    #pragma unroll
    for (int i = 0; i < 4; ++i)
        #pragma unroll
        for (int j = 0; j < 4; ++j) acc[i][j] = (v4f)0.0f;

    // prologue: 2 tiles in flight (6 loads); biases; wait tile0 (keep 3)
    STAGE(0); STAGE(1);
    if (tid < 256)      ((float*)(smem + 73728))[tid] = arow[row0 + tid];
    else if (tid < 384) ((float*)(smem + 74752))[tid - 256] = ccol[col0 + tid - 256];
    asm volatile("s_waitcnt vmcnt(3)" ::: "memory");
    __builtin_amdgcn_s_barrier();

    #pragma unroll
    for (int t = 0; t < 16; ++t) {
        if (t + 2 < 16) STAGE(t + 2);
        const int bo = (t % 3) * 24576;
        v8s af[4], bf[4];
        #pragma unroll
        for (int i = 0; i < 4; ++i) af[i] = *(const v8s*)(smem + bo + aOff + i * 2048);
        #pragma unroll
        for (int j = 0; j < 4; ++j) bf[j] = *(const v8s*)(smem + bo + bOff + j * 2048);
        __builtin_amdgcn_s_setprio(1);
        #pragma unroll
        for (int i = 0; i < 4; ++i)
            #pragma unroll
            for (int j = 0; j < 4; ++j)
                acc[i][j] = __builtin_amdgcn_mfma_f32_16x16x32_bf16(
                    bf[j], af[i], acc[i][j], 0, 0, 0);
        __builtin_amdgcn_s_setprio(0);
        if (t < 14)       asm volatile("s_waitcnt vmcnt(3)" ::: "memory");
        else if (t == 14) asm volatile("s_waitcnt vmcnt(0)" ::: "memory");
        __builtin_amdgcn_s_barrier();
    }
    #undef STAGE

    // ---- epilogue: bias+exp in-register, direct v4f stores
    const float tg = 2.0f * GAMMA;
    const float* sbr = (const float*)(smem + 73728);
    const float* sbc = (const float*)(smem + 74752);
    #pragma unroll
    for (int i = 0; i < 4; ++i) {
        const int r_l = wm * 64 + i * 16 + l15;
        const float ra = sbr[r_l];
        float* gp = out + (size_t)(row0 + r_l) * NDIM + col0 + wn * 64 + (q << 2);
        #pragma unroll
        for (int j = 0; j < 4; ++j) {
            v4f o;
            #pragma unroll
            for (int v = 0; v < 4; ++v) {
                const int c_l = wn * 64 + j * 16 + (q << 2) + v;
                o[v] = __expf(fmaf(tg, acc[i][j][v], ra + sbc[c_l]));
            }
            *(v4f*)(gp + j * 16) = o;
        }
    }
}

extern "C" void kernel_launch(void* const* d_in, const int* in_sizes, int n_in,
                              void* d_out, int out_size, void* d_ws, size_t ws_size,
                              hipStream_t stream) {
    const float* x  = (const float*)d_in[0];   // [4096,512]
    const float* sv = (const float*)d_in[1];   // [8192,512]
    float* out = (float*)d_out;

    // ws layout: xb (4 MiB) | svb (8 MiB) | arow (16 KiB) | ccol (32 KiB)
    unsigned short* xb  = (unsigned short*)d_ws;
    unsigned short* svb = xb + (size_t)MDIM * KDIM;
    float* arow = (float*)(svb + (size_t)NDIM * KDIM);
    float* ccol = arow + MDIM;

    hipLaunchKernelGGL(convert_rows, dim3(MDIM), dim3(256), 0, stream, x, xb, arow);
    hipLaunchKernelGGL(convert_rows, dim3(NDIM), dim3(256), 0, stream, sv, svb, ccol);
    hipLaunchKernelGGL(rbf_gemm, dim3((MDIM / 256) * (NDIM / 128)), dim3(512), 0,
                       stream, xb, svb, arow, ccol, out);
}

// Round 11
// 180.390 us; speedup vs baseline: 1.0493x; 1.0493x over previous
//
#include <hip/hip_runtime.h>
#include <stdint.h>

#define GAMMA 0.002f
#define MDIM 4096
#define NDIM 8192
#define KDIM 512

typedef short v8s __attribute__((ext_vector_type(8)));
typedef float v4f __attribute__((ext_vector_type(4)));

__device__ __forceinline__ unsigned short f32_to_bf16_rne(float f) {
    union { float f; uint32_t u; } v; v.f = f;
    uint32_t u = v.u;
    return (unsigned short)((u + 0x7fffu + ((u >> 16) & 1u)) >> 16);
}

__device__ __forceinline__ void gl_lds16(const void* g, void* l) {
    __builtin_amdgcn_global_load_lds(
        (const __attribute__((address_space(1))) uint32_t*)g,
        (__attribute__((address_space(3))) uint32_t*)l, 16, 0, 0);
}

// Merged converter: blocks 0..MDIM-1 handle x -> xb/arow; blocks MDIM.. handle
// sv -> svb/ccol. Same per-block work as the previous two kernels, one launch.
__global__ __launch_bounds__(256) void convert_all(
    const float* __restrict__ x, const float* __restrict__ sv,
    unsigned short* __restrict__ xb, unsigned short* __restrict__ svb,
    float* __restrict__ arow, float* __restrict__ ccol) {
    int row = blockIdx.x;
    const float* src;
    unsigned short* dst;
    float* red_out;
    if (row < MDIM) {
        src = x + (size_t)row * KDIM;
        dst = xb + (size_t)row * KDIM;
        red_out = arow + row;
    } else {
        int r2 = row - MDIM;
        src = sv + (size_t)r2 * KDIM;
        dst = svb + (size_t)r2 * KDIM;
        red_out = ccol + r2;
    }
    int t = threadIdx.x;
    float2 f = ((const float2*)src)[t];
    ushort2 b;
    b.x = f32_to_bf16_rne(f.x);
    b.y = f32_to_bf16_rne(f.y);
    ((ushort2*)dst)[t] = b;
    float s = f.x * f.x + f.y * f.y;
    #pragma unroll
    for (int off = 32; off > 0; off >>= 1) s += __shfl_down(s, off, 64);
    __shared__ float red[4];
    if ((t & 63) == 0) red[t >> 6] = s;
    __syncthreads();
    if (t == 0) *red_out = -GAMMA * (red[0] + red[1] + red[2] + red[3]);
}

// FINAL gemm = round-7 configuration (best measured: 183.7 us total), byte-
// identical. BK=32 triple-buffer, counted vmcnt(4), setprio, 3 blocks/CU,
// L2-aware XCD partition (16mt x 16nt = 2+2 MiB per XCD), 64-B-row XOR LDS,
// LDS-transpose coalesced epilogue.
// C[m,n] = exp(arow[m] + ccol[n] + 2*gamma*dot(x[m], sv[n]))
__global__ __launch_bounds__(256, 3) void rbf_gemm(
    const unsigned short* __restrict__ A,   // [4096,512] bf16
    const unsigned short* __restrict__ B,   // [8192,512] bf16
    const float* __restrict__ arow,         // [4096]  = -g*||x||^2
    const float* __restrict__ ccol,         // [8192]  = -g*||sv||^2
    float* __restrict__ out) {

    // LDS: 3 buffers x (A 8 KiB + B 8 KiB) = 48 KiB at 0..49151
    //      sb_r (128 f32) at 49152, sb_c (128 f32) at 49664.  total 50176 B.
    __shared__ __align__(16) char smem[50176];

    const int tid  = threadIdx.x;
    const int lane = tid & 63;
    const int wave = tid >> 6;          // 0..3
    const int wm   = wave >> 1;         // 0..1 : 64-row slice
    const int wn   = wave & 1;          // 0..1 : 64-col slice

    // L2-aware partition: xcd = bid&7 (round-robin dispatch), region 16m x 16n.
    const int bid = blockIdx.x;
    const int xcd = bid & 7;
    const int idx = bid >> 3;                       // 0..255 within region
    const int mt  = ((xcd & 1) << 4) | (idx & 15);  // 0..31
    const int nt  = ((xcd >> 1) << 4) | (idx >> 4); // 0..63
    const int row0 = mt << 7;
    const int col0 = nt << 7;

    // ---- staging: tile = [128 rows][32 k] bf16 (64 B/row), rows r=tid>>2 and
    // r+64, 16-B chunk c=tid&3; swizzle byte_col ^= ((r&3)<<4) applied on the
    // GLOBAL source (LDS dest stays linear: tid*16 / +4096).
    const int rS  = tid >> 2;                         // 0..63
    const int cSw = ((tid & 3) << 4) ^ ((rS & 3) << 4);
    const char* aS = (const char*)A + ((size_t)(row0 + rS) << 10) + cSw;
    const char* bS = (const char*)B + ((size_t)(col0 + rS) << 10) + cSw;
    char* dA = smem + tid * 16;
    char* dB = smem + 8192 + tid * 16;

    #define STAGE(t)                                                          \
      do {                                                                    \
        const int _b = ((t) % 3) * 16384;                                     \
        const char* _sa = aS + (t) * 64;                                      \
        const char* _sb = bS + (t) * 64;                                      \
        gl_lds16(_sa,          dA + _b);                                      \
        gl_lds16(_sa + 65536,  dA + _b + 4096);                               \
        gl_lds16(_sb,          dB + _b);                                      \
        gl_lds16(_sb + 65536,  dB + _b + 4096);                               \
      } while (0)

    // ---- fragment addresses (swizzled reads) ----
    const int q   = lane >> 4;          // 0..3 : k-chunk q*8
    const int l15 = lane & 15;
    const int ra0 = wm * 64 + l15;
    const int aOff = ra0 * 64 + (((q << 4)) ^ ((ra0 & 3) << 4));
    const int rb0 = wn * 64 + l15;
    const int bOff = 8192 + rb0 * 64 + (((q << 4)) ^ ((rb0 & 3) << 4));

    v4f acc[4][4];
    #pragma unroll
    for (int i = 0; i < 4; ++i)
        #pragma unroll
        for (int j = 0; j < 4; ++j) acc[i][j] = (v4f)0.0f;

    // prologue: 2 tiles in flight; bias loads; wait tile0 (vmcnt: 8 out, keep 4)
    STAGE(0); STAGE(1);
    if (tid < 128) ((float*)(smem + 49152))[tid] = arow[row0 + tid];
    else           ((float*)(smem + 49664))[tid - 128] = ccol[col0 + tid - 128];
    asm volatile("s_waitcnt vmcnt(4)" ::: "memory");
    __builtin_amdgcn_s_barrier();

    #pragma unroll
    for (int t = 0; t < 16; ++t) {
        if (t + 2 < 16) STAGE(t + 2);
        const int bo = (t % 3) * 16384;
        v8s af[4], bf[4];
        #pragma unroll
        for (int i = 0; i < 4; ++i) af[i] = *(const v8s*)(smem + bo + aOff + i * 1024);
        #pragma unroll
        for (int j = 0; j < 4; ++j) bf[j] = *(const v8s*)(smem + bo + bOff + j * 1024);
        __builtin_amdgcn_s_setprio(1);
        #pragma unroll
        for (int i = 0; i < 4; ++i)
            #pragma unroll
            for (int j = 0; j < 4; ++j)
                acc[i][j] = __builtin_amdgcn_mfma_f32_16x16x32_bf16(
                    bf[j], af[i], acc[i][j], 0, 0, 0);
        __builtin_amdgcn_s_setprio(0);
        if (t < 14)      asm volatile("s_waitcnt vmcnt(4)" ::: "memory");
        else if (t == 14) asm volatile("s_waitcnt vmcnt(0)" ::: "memory");
        __builtin_amdgcn_s_barrier();
    }
    #undef STAGE

    // ---- epilogue: bias+exp in-register, LDS transpose, 512-B row segments
    const float tg = 2.0f * GAMMA;
    const float* sbr = (const float*)(smem + 49152);
    const float* sbc = (const float*)(smem + 49664);
    #pragma unroll
    for (int i = 0; i < 4; ++i) {
        const float ra = sbr[wm * 64 + i * 16 + l15];
        #pragma unroll
        for (int j = 0; j < 4; ++j) {
            #pragma unroll
            for (int v = 0; v < 4; ++v) {
                const int c_l = wn * 64 + j * 16 + (q << 2) + v;
                acc[i][j][v] = __expf(fmaf(tg, acc[i][j][v], ra + sbc[c_l]));
            }
        }
    }

    float* tb = (float*)smem;            // [64][128] f32, granule-XOR swizzled
    #pragma unroll
    for (int ch = 0; ch < 2; ++ch) {
        if (wm == ch) {
            #pragma unroll
            for (int i = 0; i < 4; ++i) {
                const int rl = i * 16 + l15;           // row within chunk
                #pragma unroll
                for (int j = 0; j < 4; ++j) {
                    const int g = wn * 16 + j * 4 + q; // 16-B granule 0..31
                    *(v4f*)&tb[rl * 128 + ((g ^ (rl & 31)) << 2)] = acc[i][j];
                }
            }
        }
        __syncthreads();
        #pragma unroll
        for (int rr = 0; rr < 8; ++rr) {
            const int rl = wave * 16 + (rr << 1) + (lane >> 5);
            v4f val = *(const v4f*)&tb[rl * 128 + (((lane & 31) ^ (rl & 31)) << 2)];
            *(v4f*)(out + (size_t)(row0 + ch * 64 + rl) * NDIM + col0 +
                    ((lane & 31) << 2)) = val;
        }
        __syncthreads();
    }
}

extern "C" void kernel_launch(void* const* d_in, const int* in_sizes, int n_in,
                              void* d_out, int out_size, void* d_ws, size_t ws_size,
                              hipStream_t stream) {
    const float* x  = (const float*)d_in[0];   // [4096,512]
    const float* sv = (const float*)d_in[1];   // [8192,512]
    float* out = (float*)d_out;

    // ws layout: xb (4 MiB) | svb (8 MiB) | arow (16 KiB) | ccol (32 KiB)
    unsigned short* xb  = (unsigned short*)d_ws;
    unsigned short* svb = xb + (size_t)MDIM * KDIM;
    float* arow = (float*)(svb + (size_t)NDIM * KDIM);
    float* ccol = arow + MDIM;

    hipLaunchKernelGGL(convert_all, dim3(MDIM + NDIM), dim3(256), 0, stream,
                       x, sv, xb, svb, arow, ccol);
    hipLaunchKernelGGL(rbf_gemm, dim3((MDIM / 128) * (NDIM / 128)), dim3(256), 0,
                       stream, xb, svb, arow, ccol, out);
}